// Round 1
// baseline (568.237 us; speedup 1.0000x reference)
//
#include <hip/hip_runtime.h>

// Problem constants (GraphFourierLayer): B=32, N=4096, C_IN=128, C_OUT=128, M=256
#define BB 32
#define NN 4096
#define CI 128
#define CO 128
#define MM 256

// ---------------------------------------------------------------------------
// Stage 1: x_spec[b][m][c] = sum_n U[n][m] * x[b][n][c]
// Per-batch GEMM: (256 x 4096) x (4096 x 128). Both operands have contiguous
// non-K dims (outer-product friendly). 64x64 tile, BK=16, 4x4 per thread.
// ---------------------------------------------------------------------------
__global__ __launch_bounds__(256) void k_spec(const float* __restrict__ U,
                                              const float* __restrict__ x,
                                              float* __restrict__ xs) {
    const int b  = blockIdx.z;
    const int m0 = blockIdx.y * 64;
    const int c0 = blockIdx.x * 64;
    __shared__ float Ut[16][64];  // [k][m]
    __shared__ float Xt[16][64];  // [k][c]
    const int t  = threadIdx.x;
    const int tm = (t >> 4) * 4;  // 0..60
    const int tc = (t & 15) * 4;  // 0..60
    float acc[4][4] = {};
    for (int k0 = 0; k0 < NN; k0 += 16) {
        #pragma unroll
        for (int i = 0; i < 4; ++i) {
            int idx = t + i * 256;          // 0..1023
            int r = idx >> 6, col = idx & 63;
            Ut[r][col] = U[(k0 + r) * MM + m0 + col];
            Xt[r][col] = x[((long)b * NN + k0 + r) * CI + c0 + col];
        }
        __syncthreads();
        #pragma unroll
        for (int k = 0; k < 16; ++k) {
            float u[4], v[4];
            #pragma unroll
            for (int i = 0; i < 4; ++i) u[i] = Ut[k][tm + i];
            #pragma unroll
            for (int j = 0; j < 4; ++j) v[j] = Xt[k][tc + j];
            #pragma unroll
            for (int i = 0; i < 4; ++i)
                #pragma unroll
                for (int j = 0; j < 4; ++j)
                    acc[i][j] += u[i] * v[j];
        }
        __syncthreads();
    }
    #pragma unroll
    for (int i = 0; i < 4; ++i) {
        float4 v = make_float4(acc[i][0], acc[i][1], acc[i][2], acc[i][3]);
        *(float4*)&xs[((long)b * MM + m0 + tm + i) * CI + c0 + tc] = v;
    }
}

// ---------------------------------------------------------------------------
// Stage 2: out_spec[b][m][o] = sum_c x_spec[b][m][c] * W_real[c][o][m]
// One block per (mode m, o-half). W slice reads are stride-256 (layout
// [c][o][m]); XCD-aware swizzle keeps m-adjacent blocks on the same XCD so
// L2 absorbs the 16x cacheline overfetch.
// ---------------------------------------------------------------------------
__global__ __launch_bounds__(256) void k_mix(const float* __restrict__ xs,
                                             const float* __restrict__ W,
                                             float* __restrict__ os) {
    const int blk  = blockIdx.x;              // 0..511
    const int m    = (blk & 7) * 32 + ((blk >> 3) >> 1);  // XCD k owns m in [32k,32k+32)
    const int o0   = ((blk >> 3) & 1) * 64;
    __shared__ float Wl[CI][64];   // 32 KB  [c][o-o0]
    __shared__ float xl[BB][CI];   // 16 KB  [b][c]
    const int t = threadIdx.x;
    for (int idx = t; idx < CI * 64; idx += 256) {
        int c = idx >> 6, o = idx & 63;
        Wl[c][o] = W[((long)c * CO + o0 + o) * MM + m];
    }
    for (int idx = t; idx < BB * CI; idx += 256) {
        int b = idx >> 7, c = idx & 127;
        xl[b][c] = xs[((long)b * MM + m) * CI + c];
    }
    __syncthreads();
    const int o  = t & 63;
    const int bg = (t >> 6) * 8;              // 4 groups of 8 batches
    float acc[8] = {};
    for (int c = 0; c < CI; ++c) {
        float w = Wl[c][o];
        #pragma unroll
        for (int bb = 0; bb < 8; ++bb)
            acc[bb] += xl[bg + bb][c] * w;
    }
    #pragma unroll
    for (int bb = 0; bb < 8; ++bb)
        os[((long)(bg + bb) * MM + m) * CO + o0 + o] = acc[bb];
}

// ---------------------------------------------------------------------------
// Stage 3: out[b][n][o] = sum_m U[n][m] * out_spec[b][m][o]
// Per-batch GEMM: (4096 x 256) x (256 x 128). U has K contiguous -> store
// U tile in LDS as [n][k] with +1 padding to kill write conflicts.
// ---------------------------------------------------------------------------
__global__ __launch_bounds__(256) void k_out(const float* __restrict__ U,
                                             const float* __restrict__ os,
                                             float* __restrict__ out) {
    const int b  = blockIdx.z;
    const int n0 = blockIdx.y * 64;
    const int o0 = blockIdx.x * 64;
    __shared__ float Ut[64][17];  // [n][k], padded
    __shared__ float St[16][64];  // [k][o]
    const int t  = threadIdx.x;
    const int tn = (t >> 4) * 4;
    const int to = (t & 15) * 4;
    float acc[4][4] = {};
    for (int k0 = 0; k0 < MM; k0 += 16) {
        #pragma unroll
        for (int i = 0; i < 4; ++i) {
            int idx = t + i * 256;        // 1024 elems
            int r = idx >> 4, c = idx & 15;
            Ut[r][c] = U[(n0 + r) * MM + k0 + c];
        }
        #pragma unroll
        for (int i = 0; i < 4; ++i) {
            int idx = t + i * 256;
            int r = idx >> 6, c = idx & 63;
            St[r][c] = os[((long)b * MM + k0 + r) * CO + o0 + c];
        }
        __syncthreads();
        #pragma unroll
        for (int k = 0; k < 16; ++k) {
            float u[4], s[4];
            #pragma unroll
            for (int i = 0; i < 4; ++i) u[i] = Ut[tn + i][k];
            #pragma unroll
            for (int j = 0; j < 4; ++j) s[j] = St[k][to + j];
            #pragma unroll
            for (int i = 0; i < 4; ++i)
                #pragma unroll
                for (int j = 0; j < 4; ++j)
                    acc[i][j] += u[i] * s[j];
        }
        __syncthreads();
    }
    #pragma unroll
    for (int i = 0; i < 4; ++i) {
        float4 v = make_float4(acc[i][0], acc[i][1], acc[i][2], acc[i][3]);
        *(float4*)&out[((long)b * NN + n0 + tn + i) * CO + o0 + to] = v;
    }
}

extern "C" void kernel_launch(void* const* d_in, const int* in_sizes, int n_in,
                              void* d_out, int out_size, void* d_ws, size_t ws_size,
                              hipStream_t stream) {
    const float* x  = (const float*)d_in[0];   // [32][4096][128]
    const float* U  = (const float*)d_in[1];   // [4096][256]
    const float* Wr = (const float*)d_in[2];   // [128][128][256]
    // d_in[3] = W_imag: provably unused (output takes .real of real*complex)
    float* out = (float*)d_out;                // [32][4096][128]

    float* xs = (float*)d_ws;                        // x_spec  [32][256][128] = 4 MB
    float* os = xs + (size_t)BB * MM * CI;           // out_spec[32][256][128] = 4 MB

    k_spec<<<dim3(CI / 64, MM / 64, BB), 256, 0, stream>>>(U, x, xs);
    k_mix <<<dim3(512), 256, 0, stream>>>(xs, Wr, os);
    k_out <<<dim3(CO / 64, NN / 64, BB), 256, 0, stream>>>(U, os, out);
}

// Round 2
// 213.362 us; speedup vs baseline: 2.6632x; 2.6632x over previous
//
#include <hip/hip_runtime.h>
#include <hip/hip_bf16.h>

// GraphFourierLayer: B=32, N=4096, C_IN=128, C_OUT=128, M=256
#define BB 32
#define NN 4096
#define CI 128
#define CO 128
#define MM 256
#define KS 8           // K-split factor for stage 1 (N=4096 -> 8 chunks of 512)

typedef __hip_bfloat16 bf16;
typedef __attribute__((ext_vector_type(8))) short bf16x8;
typedef __attribute__((ext_vector_type(4))) float f32x4;

__device__ inline void gl_lds16(const void* g, void* l) {
    // 16B global->LDS DMA; LDS dest must be wave-uniform-base + lane*16.
    __builtin_amdgcn_global_load_lds(
        (const __attribute__((address_space(1))) void*)g,
        (__attribute__((address_space(3))) void*)l, 16, 0, 0);
}

// ---------------------------------------------------------------------------
// Prep 1: U fp32 [N][M] -> Un bf16 [N][M] (stage-3 A) and Ut bf16 [M][N]
// (stage-1 A, K=n contiguous). Tiled 64x64 transpose through LDS.
// ---------------------------------------------------------------------------
__global__ __launch_bounds__(256) void k_cvtU(const float* __restrict__ U,
                                              bf16* __restrict__ Un,
                                              bf16* __restrict__ Ut) {
    const int n0 = blockIdx.x * 64;
    const int m0 = blockIdx.y * 64;
    __shared__ float tile[64][65];
    const int t = threadIdx.x;
    #pragma unroll
    for (int i = 0; i < 16; ++i) {
        int lin = t + i * 256;            // 0..4095
        int r = lin >> 6, c = lin & 63;
        float v = U[(n0 + r) * MM + m0 + c];
        tile[r][c] = v;
        Un[(n0 + r) * MM + m0 + c] = __float2bfloat16(v);
    }
    __syncthreads();
    #pragma unroll
    for (int i = 0; i < 16; ++i) {
        int lin = t + i * 256;
        int r = lin >> 6, c = lin & 63;   // r = m-local, c = n-local
        Ut[(long)(m0 + r) * NN + n0 + c] = __float2bfloat16(tile[c][r]);
    }
}

// ---------------------------------------------------------------------------
// Prep 2: x fp32 [B][N][C] -> xT bf16 [B][C][N] (stage-1 B^T, K=n contiguous)
// ---------------------------------------------------------------------------
__global__ __launch_bounds__(256) void k_trx(const float* __restrict__ x,
                                             bf16* __restrict__ xT) {
    const int c0 = blockIdx.x * 64;
    const int n0 = blockIdx.y * 64;
    const int b  = blockIdx.z;
    __shared__ float tile[64][65];
    const int t = threadIdx.x;
    #pragma unroll
    for (int i = 0; i < 16; ++i) {
        int lin = t + i * 256;
        int r = lin >> 6, c = lin & 63;   // r = n-local, c = c-local
        tile[r][c] = x[((long)b * NN + n0 + r) * CI + c0 + c];
    }
    __syncthreads();
    #pragma unroll
    for (int i = 0; i < 16; ++i) {
        int lin = t + i * 256;
        int r = lin >> 6, c = lin & 63;   // r = c-local, c = n-local
        xT[((long)b * CI + c0 + r) * NN + n0 + c] = __float2bfloat16(tile[c][r]);
    }
}

// ---------------------------------------------------------------------------
// Stage 1 (MFMA, K-split): part[ks][b][m][c] = sum_{n in chunk} Ut[m][n]*xT[b][c][n]
// m97 structure: 128x128 tile, BK=32, 4 waves in 2x2, each wave 4x4 MFMA
// tiles of 16x16x32 bf16.
// ---------------------------------------------------------------------------
__global__ __launch_bounds__(256) void k_gemm1(const bf16* __restrict__ Ut,
                                               const bf16* __restrict__ xT,
                                               bf16* __restrict__ part) {
    const int ks = blockIdx.x;            // K chunk: [ks*512, ks*512+512)
    const int m0 = blockIdx.y * 128;      // m tile (2 per batch)
    const int b  = blockIdx.z;
    __shared__ __align__(16) bf16 As[128 * 32];  // [m][k] 8 KB
    __shared__ __align__(16) bf16 Bs[128 * 32];  // [c][k] 8 KB
    const int t    = threadIdx.x;
    const int lane = t & 63;
    const int wave = t >> 6;
    const int wm   = wave >> 1, wn = wave & 1;
    const int fr   = lane & 15;           // fragment row/col
    const int kg   = (lane >> 4) * 8;     // k-group offset
    f32x4 acc[4][4] = {};
    const long xbase = (long)b * CI * NN;
    for (int kt = 0; kt < 512 / 32; ++kt) {
        const int k0 = ks * 512 + kt * 32;
        #pragma unroll
        for (int i = 0; i < 2; ++i) {
            int lin = t + i * 256;        // 0..511
            int r = lin >> 2, kk = (lin & 3) * 8;
            gl_lds16(&Ut[(long)(m0 + r) * NN + k0 + kk], &As[lin * 8]);
            gl_lds16(&xT[xbase + (long)r * NN + k0 + kk], &Bs[lin * 8]);
        }
        __syncthreads();
        bf16x8 a[4], bfr[4];
        #pragma unroll
        for (int i = 0; i < 4; ++i)
            a[i] = *(const bf16x8*)&As[(wm * 64 + i * 16 + fr) * 32 + kg];
        #pragma unroll
        for (int j = 0; j < 4; ++j)
            bfr[j] = *(const bf16x8*)&Bs[(wn * 64 + j * 16 + fr) * 32 + kg];
        #pragma unroll
        for (int i = 0; i < 4; ++i)
            #pragma unroll
            for (int j = 0; j < 4; ++j)
                acc[i][j] = __builtin_amdgcn_mfma_f32_16x16x32_bf16(a[i], bfr[j], acc[i][j], 0, 0, 0);
        __syncthreads();
    }
    // C/D: col=lane&15, row=(lane>>4)*4+reg
    const int quad = (lane >> 4) * 4;
    const long pbase = ((long)ks * BB + b) * MM * CI;
    #pragma unroll
    for (int i = 0; i < 4; ++i) {
        #pragma unroll
        for (int j = 0; j < 4; ++j) {
            int mg = m0 + wm * 64 + i * 16 + quad;
            int cg = wn * 64 + j * 16 + fr;
            #pragma unroll
            for (int r = 0; r < 4; ++r)
                part[pbase + (long)(mg + r) * CI + cg] = __float2bfloat16(acc[i][j][r]);
        }
    }
}

// ---------------------------------------------------------------------------
// Stage 2: reduce K-split partials + per-mode channel mix.
// os[b][m][o] = sum_c (sum_ks part[ks][b][m][c]) * W[c][o][m]
// Block per (mode m, o-half); XCD swizzle on m.
// ---------------------------------------------------------------------------
__global__ __launch_bounds__(256) void k_mix(const bf16* __restrict__ part,
                                             const float* __restrict__ W,
                                             float* __restrict__ os) {
    const int blk = blockIdx.x;           // 0..511
    const int m   = (blk & 7) * 32 + ((blk >> 3) >> 1);
    const int o0  = ((blk >> 3) & 1) * 64;
    __shared__ float Wl[CI][64];          // 32 KB
    __shared__ float xl[BB][CI];          // 16 KB
    const int t = threadIdx.x;
    for (int idx = t; idx < CI * 64; idx += 256) {
        int c = idx >> 6, o = idx & 63;
        Wl[c][o] = W[((long)c * CO + o0 + o) * MM + m];
    }
    for (int idx = t; idx < BB * CI; idx += 256) {
        int b = idx >> 7, c = idx & 127;
        float s = 0.f;
        #pragma unroll
        for (int ks = 0; ks < KS; ++ks)
            s += __bfloat162float(part[(((long)ks * BB + b) * MM + m) * CI + c]);
        xl[b][c] = s;
    }
    __syncthreads();
    const int o  = t & 63;
    const int bg = (t >> 6) * 8;
    float acc[8] = {};
    for (int c = 0; c < CI; ++c) {
        float w = Wl[c][o];
        #pragma unroll
        for (int bb = 0; bb < 8; ++bb)
            acc[bb] += xl[bg + bb][c] * w;
    }
    #pragma unroll
    for (int bb = 0; bb < 8; ++bb)
        os[((long)(bg + bb) * MM + m) * CO + o0 + o] = acc[bb];
}

// ---------------------------------------------------------------------------
// Prep 3: os fp32 [B][M][O] -> osT bf16 [B][O][M] (stage-3 B^T, K=m contiguous)
// ---------------------------------------------------------------------------
__global__ __launch_bounds__(256) void k_tros(const float* __restrict__ os,
                                              bf16* __restrict__ osT) {
    const int o0 = blockIdx.x * 64;
    const int m0 = blockIdx.y * 64;
    const int b  = blockIdx.z;
    __shared__ float tile[64][65];
    const int t = threadIdx.x;
    #pragma unroll
    for (int i = 0; i < 16; ++i) {
        int lin = t + i * 256;
        int r = lin >> 6, c = lin & 63;   // r = m-local, c = o-local
        tile[r][c] = os[((long)b * MM + m0 + r) * CO + o0 + c];
    }
    __syncthreads();
    #pragma unroll
    for (int i = 0; i < 16; ++i) {
        int lin = t + i * 256;
        int r = lin >> 6, c = lin & 63;   // r = o-local, c = m-local
        osT[((long)b * CO + o0 + r) * MM + m0 + c] = __float2bfloat16(tile[c][r]);
    }
}

// ---------------------------------------------------------------------------
// Stage 3 (MFMA): out[b][n][o] = sum_m Un[n][m] * osT[b][o][m]. K=256, 8 iters.
// ---------------------------------------------------------------------------
__global__ __launch_bounds__(256) void k_gemm3(const bf16* __restrict__ Un,
                                               const bf16* __restrict__ osT,
                                               float* __restrict__ out) {
    const int n0 = blockIdx.x * 128;
    const int b  = blockIdx.y;
    __shared__ __align__(16) bf16 As[128 * 32];  // [n][k]
    __shared__ __align__(16) bf16 Bs[128 * 32];  // [o][k]
    const int t    = threadIdx.x;
    const int lane = t & 63;
    const int wave = t >> 6;
    const int wm   = wave >> 1, wn = wave & 1;
    const int fr   = lane & 15;
    const int kg   = (lane >> 4) * 8;
    f32x4 acc[4][4] = {};
    const long bbase = (long)b * CO * MM;
    for (int kt = 0; kt < MM / 32; ++kt) {
        const int k0 = kt * 32;
        #pragma unroll
        for (int i = 0; i < 2; ++i) {
            int lin = t + i * 256;
            int r = lin >> 2, kk = (lin & 3) * 8;
            gl_lds16(&Un[(long)(n0 + r) * MM + k0 + kk], &As[lin * 8]);
            gl_lds16(&osT[bbase + (long)r * MM + k0 + kk], &Bs[lin * 8]);
        }
        __syncthreads();
        bf16x8 a[4], bfr[4];
        #pragma unroll
        for (int i = 0; i < 4; ++i)
            a[i] = *(const bf16x8*)&As[(wm * 64 + i * 16 + fr) * 32 + kg];
        #pragma unroll
        for (int j = 0; j < 4; ++j)
            bfr[j] = *(const bf16x8*)&Bs[(wn * 64 + j * 16 + fr) * 32 + kg];
        #pragma unroll
        for (int i = 0; i < 4; ++i)
            #pragma unroll
            for (int j = 0; j < 4; ++j)
                acc[i][j] = __builtin_amdgcn_mfma_f32_16x16x32_bf16(a[i], bfr[j], acc[i][j], 0, 0, 0);
        __syncthreads();
    }
    const int quad = (lane >> 4) * 4;
    #pragma unroll
    for (int i = 0; i < 4; ++i) {
        #pragma unroll
        for (int j = 0; j < 4; ++j) {
            int ng = n0 + wm * 64 + i * 16 + quad;
            int og = wn * 64 + j * 16 + fr;
            #pragma unroll
            for (int r = 0; r < 4; ++r)
                out[((long)b * NN + ng + r) * CO + og] = acc[i][j][r];
        }
    }
}

extern "C" void kernel_launch(void* const* d_in, const int* in_sizes, int n_in,
                              void* d_out, int out_size, void* d_ws, size_t ws_size,
                              hipStream_t stream) {
    const float* x  = (const float*)d_in[0];   // [32][4096][128]
    const float* U  = (const float*)d_in[1];   // [4096][256]
    const float* Wr = (const float*)d_in[2];   // [128][128][256]
    float* out = (float*)d_out;                // [32][4096][128]

    // Workspace layout (58 MB total):
    char* p = (char*)d_ws;
    bf16* xT   = (bf16*)p;                 p += (size_t)BB * CI * NN * 2;    // 32 MB
    bf16* part = (bf16*)p;                 p += (size_t)KS * BB * MM * CI * 2; // 16 MB
    bf16* Ut   = (bf16*)p;                 p += (size_t)MM * NN * 2;         // 2 MB
    bf16* Un   = (bf16*)p;                 p += (size_t)NN * MM * 2;         // 2 MB
    bf16* osT  = (bf16*)p;                 p += (size_t)BB * CO * MM * 2;    // 2 MB
    float* os  = (float*)p;                p += (size_t)BB * MM * CO * 4;    // 4 MB

    k_cvtU <<<dim3(NN / 64, MM / 64), 256, 0, stream>>>(U, Un, Ut);
    k_trx  <<<dim3(CI / 64, NN / 64, BB), 256, 0, stream>>>(x, xT);
    k_gemm1<<<dim3(KS, MM / 128, BB), 256, 0, stream>>>(Ut, xT, part);
    k_mix  <<<dim3(512), 256, 0, stream>>>(part, Wr, os);
    k_tros <<<dim3(CO / 64, MM / 64, BB), 256, 0, stream>>>(os, osT);
    k_gemm3<<<dim3(NN / 128, BB), 256, 0, stream>>>(Un, osT, out);
}

// Round 3
// 200.651 us; speedup vs baseline: 2.8320x; 1.0634x over previous
//
#include <hip/hip_runtime.h>
#include <hip/hip_bf16.h>

// GraphFourierLayer: B=32, N=4096, C_IN=128, C_OUT=128, M=256
#define BB 32
#define NN 4096
#define CI 128
#define CO 128
#define MM 256
#define KS 8           // K-split factor for stage 1 (N=4096 -> 8 chunks of 512)

typedef __hip_bfloat16 bf16;
typedef __attribute__((ext_vector_type(8))) short bf16x8;
typedef __attribute__((ext_vector_type(4))) float f32x4;

__device__ inline void gl_lds16(const void* g, void* l) {
    __builtin_amdgcn_global_load_lds(
        (const __attribute__((address_space(1))) void*)g,
        (__attribute__((address_space(3))) void*)l, 16, 0, 0);
}

// ---------------------------------------------------------------------------
// Prep 1: U fp32 [N][M] -> Un bf16 [N][M] (stage-3 A) and Ut bf16 [M][N]
// ---------------------------------------------------------------------------
__global__ __launch_bounds__(256) void k_cvtU(const float* __restrict__ U,
                                              bf16* __restrict__ Un,
                                              bf16* __restrict__ Ut) {
    const int n0 = blockIdx.x * 64;
    const int m0 = blockIdx.y * 64;
    __shared__ float tile[64][65];
    const int t = threadIdx.x;
    #pragma unroll
    for (int i = 0; i < 16; ++i) {
        int lin = t + i * 256;
        int r = lin >> 6, c = lin & 63;
        float v = U[(n0 + r) * MM + m0 + c];
        tile[r][c] = v;
        Un[(n0 + r) * MM + m0 + c] = __float2bfloat16(v);
    }
    __syncthreads();
    #pragma unroll
    for (int i = 0; i < 16; ++i) {
        int lin = t + i * 256;
        int r = lin >> 6, c = lin & 63;   // r = m-local, c = n-local
        Ut[(long)(m0 + r) * NN + n0 + c] = __float2bfloat16(tile[c][r]);
    }
}

// ---------------------------------------------------------------------------
// Prep 2: x fp32 [B][N][C] -> xT bf16 [B][C][N]
// ---------------------------------------------------------------------------
__global__ __launch_bounds__(256) void k_trx(const float* __restrict__ x,
                                             bf16* __restrict__ xT) {
    const int c0 = blockIdx.x * 64;
    const int n0 = blockIdx.y * 64;
    const int b  = blockIdx.z;
    __shared__ float tile[64][65];
    const int t = threadIdx.x;
    #pragma unroll
    for (int i = 0; i < 16; ++i) {
        int lin = t + i * 256;
        int r = lin >> 6, c = lin & 63;   // r = n-local, c = c-local
        tile[r][c] = x[((long)b * NN + n0 + r) * CI + c0 + c];
    }
    __syncthreads();
    #pragma unroll
    for (int i = 0; i < 16; ++i) {
        int lin = t + i * 256;
        int r = lin >> 6, c = lin & 63;   // r = c-local, c = n-local
        xT[((long)b * CI + c0 + r) * NN + n0 + c] = __float2bfloat16(tile[c][r]);
    }
}

// ---------------------------------------------------------------------------
// Prep 3 (NEW): W fp32 [C][O][M] -> Wt bf16 [M][C][O]. Coalesced tiled
// transpose of the (o,m) planes per c; kills the per-mode stride-1KB gather
// that made old k_mix latency-bound (40 us, 519 GB/s).
// ---------------------------------------------------------------------------
__global__ __launch_bounds__(256) void k_wt(const float* __restrict__ W,
                                            bf16* __restrict__ Wt) {
    const int m0 = blockIdx.x * 64;   // 4 tiles
    const int o0 = blockIdx.y * 64;   // 2 tiles
    const int c  = blockIdx.z;        // 128
    __shared__ float tile[64][65];
    const int t = threadIdx.x;
    #pragma unroll
    for (int i = 0; i < 16; ++i) {
        int lin = t + i * 256;
        int r = lin >> 6, col = lin & 63;  // r = o-local, col = m-local (coalesced)
        tile[r][col] = W[((long)c * CO + o0 + r) * MM + m0 + col];
    }
    __syncthreads();
    #pragma unroll
    for (int i = 0; i < 16; ++i) {
        int lin = t + i * 256;
        int r = lin >> 6, col = lin & 63;  // r = m-local, col = o-local (coalesced)
        Wt[((long)(m0 + r) * CI + c) * CO + o0 + col] = __float2bfloat16(tile[col][r]);
    }
}

// ---------------------------------------------------------------------------
// Stage 1 (MFMA, K-split): part[ks][b][m][c] = sum_n Ut[m][n]*xT[b][c][n]
// ---------------------------------------------------------------------------
__global__ __launch_bounds__(256) void k_gemm1(const bf16* __restrict__ Ut,
                                               const bf16* __restrict__ xT,
                                               bf16* __restrict__ part) {
    const int ks = blockIdx.x;
    const int m0 = blockIdx.y * 128;
    const int b  = blockIdx.z;
    __shared__ __align__(16) bf16 As[128 * 32];
    __shared__ __align__(16) bf16 Bs[128 * 32];
    const int t    = threadIdx.x;
    const int lane = t & 63;
    const int wave = t >> 6;
    const int wm   = wave >> 1, wn = wave & 1;
    const int fr   = lane & 15;
    const int kg   = (lane >> 4) * 8;
    f32x4 acc[4][4] = {};
    const long xbase = (long)b * CI * NN;
    for (int kt = 0; kt < 512 / 32; ++kt) {
        const int k0 = ks * 512 + kt * 32;
        #pragma unroll
        for (int i = 0; i < 2; ++i) {
            int lin = t + i * 256;
            int r = lin >> 2, kk = (lin & 3) * 8;
            gl_lds16(&Ut[(long)(m0 + r) * NN + k0 + kk], &As[lin * 8]);
            gl_lds16(&xT[xbase + (long)r * NN + k0 + kk], &Bs[lin * 8]);
        }
        __syncthreads();
        bf16x8 a[4], bfr[4];
        #pragma unroll
        for (int i = 0; i < 4; ++i)
            a[i] = *(const bf16x8*)&As[(wm * 64 + i * 16 + fr) * 32 + kg];
        #pragma unroll
        for (int j = 0; j < 4; ++j)
            bfr[j] = *(const bf16x8*)&Bs[(wn * 64 + j * 16 + fr) * 32 + kg];
        #pragma unroll
        for (int i = 0; i < 4; ++i)
            #pragma unroll
            for (int j = 0; j < 4; ++j)
                acc[i][j] = __builtin_amdgcn_mfma_f32_16x16x32_bf16(a[i], bfr[j], acc[i][j], 0, 0, 0);
        __syncthreads();
    }
    const int quad = (lane >> 4) * 4;
    const long pbase = ((long)ks * BB + b) * MM * CI;
    #pragma unroll
    for (int i = 0; i < 4; ++i) {
        #pragma unroll
        for (int j = 0; j < 4; ++j) {
            int mg = m0 + wm * 64 + i * 16 + quad;
            int cg = wn * 64 + j * 16 + fr;
            #pragma unroll
            for (int r = 0; r < 4; ++r)
                part[pbase + (long)(mg + r) * CI + cg] = __float2bfloat16(acc[i][j][r]);
        }
    }
}

// ---------------------------------------------------------------------------
// Stage 2 (REWRITTEN): reduce K-split partials + per-mode channel mix.
// osT[b][o][m] = sum_c (sum_ks part[ks][b][m][c]) * Wt[m][c][o]
// Block = (mode m, o-half). xl stored TRANSPOSED [c][b] so the 8-batch
// x-vector is a wave-broadcast b128 read; Wl reads are lane-contiguous.
// Writes osT directly (scattered 2-B stores, merged in L2) -> k_tros removed.
// ---------------------------------------------------------------------------
__global__ __launch_bounds__(256) void k_mix(const bf16* __restrict__ part,
                                             const bf16* __restrict__ Wt,
                                             bf16* __restrict__ osT) {
    const int blk = blockIdx.x;               // 0..511
    const int mi  = blk >> 1;
    const int m   = (mi & 7) * 32 + (mi >> 3); // XCD swizzle on mode
    const int o0  = (blk & 1) * 64;
    __shared__ float Wl[CI][64];              // 32 KB   [c][o']
    __shared__ float xl[CI][36];              // 18.4 KB [c][b] (+4 pad)
    const int t = threadIdx.x;
    // Fill Wl: coalesced bf16x8 rows from Wt[m][c][o0..]
    const long wb = (long)m * CI * CO;
    #pragma unroll
    for (int i = 0; i < 4; ++i) {
        int ch = t + i * 256;                 // 0..1023
        int c = ch >> 3, og = (ch & 7) * 8;
        bf16x8 v = *(const bf16x8*)&Wt[wb + (long)c * CO + o0 + og];
        #pragma unroll
        for (int j = 0; j < 8; ++j) Wl[c][og + j] = __bfloat162float(((const bf16*)&v)[j]);
    }
    // Fill xl (transposed) with the 8-way K-split reduce
    #pragma unroll
    for (int i = 0; i < 2; ++i) {
        int ch = t + i * 256;                 // 0..511
        int b = ch >> 4, c8 = (ch & 15) * 8;
        float s[8] = {};
        #pragma unroll
        for (int ks = 0; ks < KS; ++ks) {
            bf16x8 v = *(const bf16x8*)&part[(((long)ks * BB + b) * MM + m) * CI + c8];
            #pragma unroll
            for (int j = 0; j < 8; ++j) s[j] += __bfloat162float(((const bf16*)&v)[j]);
        }
        #pragma unroll
        for (int j = 0; j < 8; ++j) xl[c8 + j][b] = s[j];
    }
    __syncthreads();
    const int op = t & 63;                    // o' = lane -> conflict-free Wl
    const int bq = t >> 6;                    // = wave id -> broadcast xl reads
    float acc[8] = {};
    for (int c = 0; c < CI; ++c) {
        float w = Wl[c][op];
        #pragma unroll
        for (int j = 0; j < 8; ++j)
            acc[j] += xl[c][bq * 8 + j] * w;
    }
    #pragma unroll
    for (int j = 0; j < 8; ++j)
        osT[((long)(bq * 8 + j) * CO + o0 + op) * MM + m] = __float2bfloat16(acc[j]);
}

// ---------------------------------------------------------------------------
// Stage 3 (MFMA): out[b][n][o] = sum_m Un[n][m] * osT[b][o][m]. K=256.
// ---------------------------------------------------------------------------
__global__ __launch_bounds__(256) void k_gemm3(const bf16* __restrict__ Un,
                                               const bf16* __restrict__ osT,
                                               float* __restrict__ out) {
    const int n0 = blockIdx.x * 128;
    const int b  = blockIdx.y;
    __shared__ __align__(16) bf16 As[128 * 32];
    __shared__ __align__(16) bf16 Bs[128 * 32];
    const int t    = threadIdx.x;
    const int lane = t & 63;
    const int wave = t >> 6;
    const int wm   = wave >> 1, wn = wave & 1;
    const int fr   = lane & 15;
    const int kg   = (lane >> 4) * 8;
    f32x4 acc[4][4] = {};
    const long bbase = (long)b * CO * MM;
    for (int kt = 0; kt < MM / 32; ++kt) {
        const int k0 = kt * 32;
        #pragma unroll
        for (int i = 0; i < 2; ++i) {
            int lin = t + i * 256;
            int r = lin >> 2, kk = (lin & 3) * 8;
            gl_lds16(&Un[(long)(n0 + r) * MM + k0 + kk], &As[lin * 8]);
            gl_lds16(&osT[bbase + (long)r * MM + k0 + kk], &Bs[lin * 8]);
        }
        __syncthreads();
        bf16x8 a[4], bfr[4];
        #pragma unroll
        for (int i = 0; i < 4; ++i)
            a[i] = *(const bf16x8*)&As[(wm * 64 + i * 16 + fr) * 32 + kg];
        #pragma unroll
        for (int j = 0; j < 4; ++j)
            bfr[j] = *(const bf16x8*)&Bs[(wn * 64 + j * 16 + fr) * 32 + kg];
        #pragma unroll
        for (int i = 0; i < 4; ++i)
            #pragma unroll
            for (int j = 0; j < 4; ++j)
                acc[i][j] = __builtin_amdgcn_mfma_f32_16x16x32_bf16(a[i], bfr[j], acc[i][j], 0, 0, 0);
        __syncthreads();
    }
    const int quad = (lane >> 4) * 4;
    #pragma unroll
    for (int i = 0; i < 4; ++i) {
        #pragma unroll
        for (int j = 0; j < 4; ++j) {
            int ng = n0 + wm * 64 + i * 16 + quad;
            int og = wn * 64 + j * 16 + fr;
            #pragma unroll
            for (int r = 0; r < 4; ++r)
                out[((long)b * NN + ng + r) * CO + og] = acc[i][j][r];
        }
    }
}

extern "C" void kernel_launch(void* const* d_in, const int* in_sizes, int n_in,
                              void* d_out, int out_size, void* d_ws, size_t ws_size,
                              hipStream_t stream) {
    const float* x  = (const float*)d_in[0];   // [32][4096][128]
    const float* U  = (const float*)d_in[1];   // [4096][256]
    const float* Wr = (const float*)d_in[2];   // [128][128][256]
    float* out = (float*)d_out;                // [32][4096][128]

    char* p = (char*)d_ws;
    bf16* xT   = (bf16*)p;  p += (size_t)BB * CI * NN * 2;        // 32 MB
    bf16* part = (bf16*)p;  p += (size_t)KS * BB * MM * CI * 2;   // 16 MB
    bf16* Ut   = (bf16*)p;  p += (size_t)MM * NN * 2;             // 2 MB
    bf16* Un   = (bf16*)p;  p += (size_t)NN * MM * 2;             // 2 MB
    bf16* osT  = (bf16*)p;  p += (size_t)BB * CO * MM * 2;        // 2 MB
    bf16* Wt   = (bf16*)p;  p += (size_t)MM * CI * CO * 2;        // 8 MB

    k_cvtU <<<dim3(NN / 64, MM / 64), 256, 0, stream>>>(U, Un, Ut);
    k_trx  <<<dim3(CI / 64, NN / 64, BB), 256, 0, stream>>>(x, xT);
    k_wt   <<<dim3(MM / 64, CO / 64, CI), 256, 0, stream>>>(Wr, Wt);
    k_gemm1<<<dim3(KS, MM / 128, BB), 256, 0, stream>>>(Ut, xT, part);
    k_mix  <<<dim3(512), 256, 0, stream>>>(part, Wt, osT);
    k_gemm3<<<dim3(NN / 128, BB), 256, 0, stream>>>(Un, osT, out);
}